// Round 12
// baseline (257.707 us; speedup 1.0000x reference)
//
#include <hip/hip_runtime.h>
#include <math.h>

#define N_NODES 50000
#define N_EDGES 800000
#define HID 16
#define SCAN_BLOCKS ((N_NODES + 255) / 256)   // 196
#define EPT 4                                  // edges per thread in decoder

// ---------------------------------------------------------------------------
// count: cnt_all[dst]++ for EVERY edge; cnt_act[dst]++ for same-region edges.
// ---------------------------------------------------------------------------
__global__ void count_kernel(const int* __restrict__ src,
                             const int* __restrict__ dst,
                             const int* __restrict__ region,
                             int* __restrict__ cnt_all,
                             int* __restrict__ cnt_act) {
    int e = blockIdx.x * blockDim.x + threadIdx.x;
    int s = src[e];
    int d = dst[e];
    atomicAdd(cnt_all + d, 1);
    if (region[s] == region[d]) atomicAdd(cnt_act + d, 1);
}

// ---------------------------------------------------------------------------
// hierarchical exclusive scan of cnt_act -> row_ptr (3 wide kernels)
// ---------------------------------------------------------------------------
__global__ void scanA_kernel(const int* __restrict__ cnt_act,
                             int* __restrict__ blockSums) {
    __shared__ int red[256];
    int i = blockIdx.x * 256 + threadIdx.x;
    red[threadIdx.x] = (i < N_NODES) ? cnt_act[i] : 0;
    __syncthreads();
    for (int off = 128; off > 0; off >>= 1) {
        if (threadIdx.x < off) red[threadIdx.x] += red[threadIdx.x + off];
        __syncthreads();
    }
    if (threadIdx.x == 0) blockSums[blockIdx.x] = red[0];
}

__global__ void scanB_kernel(const int* __restrict__ blockSums,
                             int* __restrict__ blockOff) {
    __shared__ int s[256];
    int t = threadIdx.x;
    s[t] = (t < SCAN_BLOCKS) ? blockSums[t] : 0;
    __syncthreads();
    for (int off = 1; off < 256; off <<= 1) {
        int v = (t >= off) ? s[t - off] : 0;
        __syncthreads();
        s[t] += v;
        __syncthreads();
    }
    if (t < SCAN_BLOCKS) blockOff[t] = (t == 0) ? 0 : s[t - 1];
}

__global__ void scanC_kernel(const int* __restrict__ cnt_act,
                             const int* __restrict__ blockOff,
                             int* __restrict__ row_ptr) {
    __shared__ int s[256];
    int t = threadIdx.x;
    int i = blockIdx.x * 256 + t;
    int v = (i < N_NODES) ? cnt_act[i] : 0;
    s[t] = v;
    __syncthreads();
    for (int off = 1; off < 256; off <<= 1) {
        int u = (t >= off) ? s[t - off] : 0;
        __syncthreads();
        s[t] += u;
        __syncthreads();
    }
    if (i < N_NODES) row_ptr[i] = blockOff[blockIdx.x] + s[t] - v;  // exclusive
}

// ---------------------------------------------------------------------------
// fill: scatter active edge ids into CSR slots (csr_eid lives in d_out).
// ---------------------------------------------------------------------------
__global__ void fill_kernel(const int* __restrict__ src,
                            const int* __restrict__ dst,
                            const int* __restrict__ region,
                            const int* __restrict__ row_ptr,
                            int* __restrict__ cursor,
                            int* __restrict__ csr_eid) {
    int e = blockIdx.x * blockDim.x + threadIdx.x;
    int s = src[e];
    int d = dst[e];
    if (region[s] == region[d]) {
        int pos = row_ptr[d] + atomicAdd(cursor + d, 1);
        csr_eid[pos] = e;
    }
}

// ---------------------------------------------------------------------------
// fused layer (gather, NO atomics): 16 lanes per node, lane j owns channel j.
// WRITE_UV=false: write h_out[n][j] (stride 16).
// WRITE_UV=true (layer 3): write uv[n*32+j]=u_j, uv[n*32+16+j]=v_j where
//   u = Wd1[0:16]^T h_out,  v = Wd1[16:32]^T h_out  (decoder layer-1 split).
// ---------------------------------------------------------------------------
template <int IN_C, bool WRITE_UV>
__global__ void layer_gather(const float* __restrict__ x,       // pos at n*16+0..1
                             const float* __restrict__ hbase,   // stride 16
                             const int* __restrict__ src,
                             const int* __restrict__ csr_eid,
                             const int* __restrict__ row_ptr,
                             const int* __restrict__ cnt_act,
                             const int* __restrict__ cnt_all,
                             const float* __restrict__ Win,     // (2, IN_C*16)
                             const float* __restrict__ bin,     // (IN_C*16)
                             const float* __restrict__ Wout,    // (16,16)
                             const float* __restrict__ bout,    // (16)
                             const float* __restrict__ Wd1,     // (32,16) or null
                             float* __restrict__ hout) {
    int t = blockIdx.x * blockDim.x + threadIdx.x;
    int n = t >> 4;                 // node
    int j = t & 15;                 // output channel

    float w0[IN_C], w1[IN_C], bb[IN_C];
#pragma unroll
    for (int c = 0; c < IN_C; ++c) {
        w0[c] = Win[c * HID + j];
        w1[c] = Win[IN_C * HID + c * HID + j];
        bb[c] = bin[c * HID + j];
    }

    float px = x[n * 16 + 0];
    float py = x[n * 16 + 1];

    int beg = row_ptr[n];
    int cntA = cnt_act[n];

    float msg = 0.0f;
    for (int k = 0; k < cntA; ++k) {
        int e = csr_eid[beg + k];
        int s = src[e];
        float rx = px - x[s * 16 + 0];     // rel = pos[dst]-pos[src], dst==n
        float ry = py - x[s * 16 + 1];
        const float* hs = hbase + s * 16;
        float m = 0.0f;
#pragma unroll
        for (int c = 0; c < IN_C; ++c) {
            float sp = fmaf(rx, w0[c], fmaf(ry, w1[c], bb[c]));
            sp = fmaxf(sp, 0.0f);
            m = fmaf(hs[c], sp, m);
        }
        msg += m;
    }

    float inv = 1.0f / fmaxf((float)cnt_all[n], 1.0f);
    float a = msg * inv;                    // this lane's a_j

    int lane_base = (threadIdx.x & 63) & 0x30;
    float o = bout[j];
#pragma unroll
    for (int c = 0; c < HID; ++c) {
        float ac = __shfl(a, lane_base + c, 64);
        o = fmaf(ac, Wout[c * HID + j], o);
    }
    float hval = fmaxf(o, 0.0f);

    if (!WRITE_UV) {
        hout[n * HID + j] = hval;
    } else {
        // u_j = sum_c h_c * Wd1[c][j];  v_j = sum_c h_c * Wd1[16+c][j]
        float u = 0.0f, v = 0.0f;
#pragma unroll
        for (int c = 0; c < HID; ++c) {
            float hc = __shfl(hval, lane_base + c, 64);
            u = fmaf(hc, Wd1[c * HID + j], u);
            v = fmaf(hc, Wd1[(HID + c) * HID + j], v);
        }
        hout[n * 32 + j]       = u;
        hout[n * 32 + 16 + j]  = v;
    }
}

// ---------------------------------------------------------------------------
// decoder (4 edges/thread): d1 = relu(u_src + v_dst + b1);
//   d2 = d1 @ Wd2 + b2;  out = sigmoid(relu(d2) . Wd3 + b3)
// Wd2 row loads amortized over 4 edges. Runs LAST; overwrites d_out (csr_eid).
// ---------------------------------------------------------------------------
__global__ void decoder_kernel(const float* __restrict__ uv,   // (N,32): u|v
                               const int* __restrict__ src,
                               const int* __restrict__ dst,
                               const float* __restrict__ bd1,  // (16)
                               const float* __restrict__ Wd2,  // (16,16)
                               const float* __restrict__ bd2,  // (16)
                               const float* __restrict__ Wd3,  // (16,1)
                               const float* __restrict__ bd3,  // (1)
                               float* __restrict__ out) {
    int i = blockIdx.x * blockDim.x + threadIdx.x;
    if (i * EPT >= N_EDGES) return;

    const int4* src4 = (const int4*)src;
    const int4* dst4 = (const int4*)dst;
    int4 s4 = src4[i];
    int4 d4 = dst4[i];
    int ss[EPT] = {s4.x, s4.y, s4.z, s4.w};
    int dd[EPT] = {d4.x, d4.y, d4.z, d4.w};

    // bias b1 once
    float b1[HID];
    const float4* b1p = (const float4*)bd1;
#pragma unroll
    for (int q = 0; q < 4; ++q) {
        float4 b = b1p[q];
        b1[q*4+0] = b.x; b1[q*4+1] = b.y; b1[q*4+2] = b.z; b1[q*4+3] = b.w;
    }

    float d1[EPT][HID];
#pragma unroll
    for (int e = 0; e < EPT; ++e) {
        const float4* us = (const float4*)(uv + (size_t)ss[e] * 32);
        const float4* vd = (const float4*)(uv + (size_t)dd[e] * 32 + 16);
#pragma unroll
        for (int q = 0; q < 4; ++q) {
            float4 a = us[q];
            float4 b = vd[q];
            d1[e][q*4+0] = fmaxf(a.x + b.x + b1[q*4+0], 0.0f);
            d1[e][q*4+1] = fmaxf(a.y + b.y + b1[q*4+1], 0.0f);
            d1[e][q*4+2] = fmaxf(a.z + b.z + b1[q*4+2], 0.0f);
            d1[e][q*4+3] = fmaxf(a.w + b.w + b1[q*4+3], 0.0f);
        }
    }

    float acc[EPT][HID];
    const float4* b2p = (const float4*)bd2;
#pragma unroll
    for (int q = 0; q < 4; ++q) {
        float4 b = b2p[q];
#pragma unroll
        for (int e = 0; e < EPT; ++e) {
            acc[e][q*4+0] = b.x; acc[e][q*4+1] = b.y;
            acc[e][q*4+2] = b.z; acc[e][q*4+3] = b.w;
        }
    }

#pragma unroll
    for (int c = 0; c < HID; ++c) {
        const float4* wr = (const float4*)(Wd2 + c * HID);
        float w[HID];
#pragma unroll
        for (int q = 0; q < 4; ++q) {
            float4 wv = wr[q];
            w[q*4+0] = wv.x; w[q*4+1] = wv.y; w[q*4+2] = wv.z; w[q*4+3] = wv.w;
        }
#pragma unroll
        for (int e = 0; e < EPT; ++e) {
            float dc = d1[e][c];
#pragma unroll
            for (int j = 0; j < HID; ++j) acc[e][j] = fmaf(dc, w[j], acc[e][j]);
        }
    }

    float w3[HID];
    const float4* w3p = (const float4*)Wd3;
#pragma unroll
    for (int q = 0; q < 4; ++q) {
        float4 wv = w3p[q];
        w3[q*4+0] = wv.x; w3[q*4+1] = wv.y; w3[q*4+2] = wv.z; w3[q*4+3] = wv.w;
    }
    float b3 = bd3[0];

    float4 res;
    float r[EPT];
#pragma unroll
    for (int e = 0; e < EPT; ++e) {
        float o = b3;
#pragma unroll
        for (int j = 0; j < HID; ++j) o = fmaf(fmaxf(acc[e][j], 0.0f), w3[j], o);
        r[e] = 1.0f / (1.0f + __expf(-o));
    }
    res.x = r[0]; res.y = r[1]; res.z = r[2]; res.w = r[3];
    ((float4*)out)[i] = res;
}

// ---------------------------------------------------------------------------
extern "C" void kernel_launch(void* const* d_in, const int* in_sizes, int n_in,
                              void* d_out, int out_size, void* d_ws, size_t ws_size,
                              hipStream_t stream) {
    const float* x      = (const float*)d_in[0];
    const int*   edge   = (const int*)d_in[1];   // (2, E): src row then dst row
    const int*   region = (const int*)d_in[2];
    const float* W_in1  = (const float*)d_in[3];
    const float* b_in1  = (const float*)d_in[4];
    const float* W_out1 = (const float*)d_in[5];
    const float* b_out1 = (const float*)d_in[6];
    const float* W_in2  = (const float*)d_in[7];
    const float* b_in2  = (const float*)d_in[8];
    const float* W_out2 = (const float*)d_in[9];
    const float* b_out2 = (const float*)d_in[10];
    const float* W_in3  = (const float*)d_in[11];
    const float* b_in3  = (const float*)d_in[12];
    const float* W_out3 = (const float*)d_in[13];
    const float* b_out3 = (const float*)d_in[14];
    const float* Wd1    = (const float*)d_in[15];
    const float* bd1    = (const float*)d_in[16];
    const float* Wd2    = (const float*)d_in[17];
    const float* bd2    = (const float*)d_in[18];
    const float* Wd3    = (const float*)d_in[19];
    const float* bd3    = (const float*)d_in[20];
    float* out = (float*)d_out;

    const int* src = edge;
    const int* dst = edge + N_EDGES;

    // workspace (~14 MB; ws_size ≈ 268 MB per harness poison-fill counter):
    //   hA[800000 f] hB[800000 f] uv[1600000 f]
    //   cnt_all/cnt_act/row_ptr/cursor[50000 i each] blockSums/blockOff[256 i]
    // csr_eid (≤800000 ints) lives in d_out; decoder overwrites it last.
    float* ws        = (float*)d_ws;
    float* hA        = ws;
    float* hB        = hA + N_NODES * HID;
    float* uv        = hB + N_NODES * HID;
    int*   cnt_all   = (int*)(uv + N_NODES * 32);
    int*   cnt_act   = cnt_all + N_NODES;
    int*   row_ptr   = cnt_act + N_NODES;
    int*   cursor    = row_ptr + N_NODES;
    int*   blockSums = cursor + N_NODES;
    int*   blockOff  = blockSums + 256;
    int*   csr_eid   = (int*)d_out;

    const int BLK = 256;
    const int egrid = N_EDGES / BLK;          // 3125, exact
    const int lgrid = N_NODES * HID / BLK;    // 3125, exact (16 lanes/node)
    const int dgrid = (N_EDGES / EPT + BLK - 1) / BLK;   // 782

    // zero cnt_all + cnt_act + row_ptr + cursor (contiguous 4*50000 ints)
    hipMemsetAsync(cnt_all, 0, (size_t)(4 * N_NODES) * sizeof(int), stream);

    count_kernel<<<egrid, BLK, 0, stream>>>(src, dst, region, cnt_all, cnt_act);
    scanA_kernel<<<SCAN_BLOCKS, 256, 0, stream>>>(cnt_act, blockSums);
    scanB_kernel<<<1, 256, 0, stream>>>(blockSums, blockOff);
    scanC_kernel<<<SCAN_BLOCKS, 256, 0, stream>>>(cnt_act, blockOff, row_ptr);
    fill_kernel<<<egrid, BLK, 0, stream>>>(src, dst, region, row_ptr, cursor, csr_eid);

    layer_gather<14, false><<<lgrid, BLK, 0, stream>>>(x, x + 2, src, csr_eid, row_ptr,
                                                       cnt_act, cnt_all, W_in1, b_in1,
                                                       W_out1, b_out1, nullptr, hA);
    layer_gather<16, false><<<lgrid, BLK, 0, stream>>>(x, hA, src, csr_eid, row_ptr,
                                                       cnt_act, cnt_all, W_in2, b_in2,
                                                       W_out2, b_out2, nullptr, hB);
    layer_gather<16, true><<<lgrid, BLK, 0, stream>>>(x, hB, src, csr_eid, row_ptr,
                                                      cnt_act, cnt_all, W_in3, b_in3,
                                                      W_out3, b_out3, Wd1, uv);

    decoder_kernel<<<dgrid, BLK, 0, stream>>>(uv, src, dst, bd1, Wd2, bd2, Wd3, bd3, out);
}